// Round 1
// baseline (290.054 us; speedup 1.0000x reference)
//
#include <hip/hip_runtime.h>

#define T_DIM 8192
#define D_DIM 256
#define N_DIM 64
#define LOG2E 1.44269504f

typedef __bf16 bf16x8 __attribute__((ext_vector_type(8)));
typedef __bf16 bf16x4 __attribute__((ext_vector_type(4)));
typedef float f32x16 __attribute__((ext_vector_type(16)));

__device__ __forceinline__ f32x16 zero16() {
  f32x16 v;
#pragma unroll
  for (int i = 0; i < 16; ++i) v[i] = 0.f;
  return v;
}

// DHf: fragment-major. Row-group G=t>>5, chunk c=kk*2+h, lane l31:
// DHf[G*2048 + c*256 + l31*8 .. +7] = DH[n=c*8+e][t=G*32+l31].

// ---------------------------------------------------------------------------
// K1: DHf (bf16, fragment-major) via split-bf16 MFMA, lbe[t]=lb*log2e,
//     rowsum[t]=0. grid 128 x 256.  (unchanged)
// ---------------------------------------------------------------------------
__global__ __launch_bounds__(256) void k_dh(const float* __restrict__ H,
                                            const float* __restrict__ Dm,
                                            __bf16* __restrict__ DHf,
                                            float* __restrict__ lbe,
                                            float* __restrict__ rowsum) {
  __shared__ __bf16 HlThi[64 * 264];
  __shared__ __bf16 HlTlo[64 * 264];
  __shared__ __bf16 DHs[64 * 72];
  const int tid = threadIdx.x;
  const int t0 = blockIdx.x * 64;
  const int lane = tid & 63;
  const int wave = tid >> 6;
  const int h = lane >> 5;
  const int l31 = lane & 31;
  const float4* H4 = (const float4*)H;
#pragma unroll
  for (int r = 0; r < 16; ++r) {
    int idx = r * 256 + tid;
    int d = idx >> 4, tc = idx & 15;
    float4 v = H4[(size_t)d * (T_DIM / 4) + (t0 >> 2) + tc];
    float vv[4] = {v.x, v.y, v.z, v.w};
#pragma unroll
    for (int i = 0; i < 4; ++i) {
      __bf16 hi = (__bf16)vv[i];
      float lo = vv[i] - (float)hi;
      HlThi[(tc * 4 + i) * 264 + d] = hi;
      HlTlo[(tc * 4 + i) * 264 + d] = (__bf16)lo;
    }
  }
  __syncthreads();
  const int tt = wave & 1, nh = wave >> 1;
  const int m = tt * 32 + l31;
  const int n = nh * 32 + l31;
  f32x16 c = zero16();
  for (int kk = 0; kk < 16; ++kk) {
    bf16x8 ahi = *(const bf16x8*)&HlThi[m * 264 + kk * 16 + h * 8];
    bf16x8 alo = *(const bf16x8*)&HlTlo[m * 264 + kk * 16 + h * 8];
    const float4* dp = (const float4*)(Dm + (size_t)n * 256 + kk * 16 + h * 8);
    float4 b0 = dp[0], b1 = dp[1];
    float bv[8] = {b0.x, b0.y, b0.z, b0.w, b1.x, b1.y, b1.z, b1.w};
    bf16x8 bhi, blo;
#pragma unroll
    for (int i = 0; i < 8; ++i) {
      __bf16 hi = (__bf16)bv[i];
      bhi[i] = hi;
      blo[i] = (__bf16)(bv[i] - (float)hi);
    }
    c = __builtin_amdgcn_mfma_f32_32x32x16_bf16(ahi, bhi, c, 0, 0, 0);
    c = __builtin_amdgcn_mfma_f32_32x32x16_bf16(ahi, blo, c, 0, 0, 0);
    c = __builtin_amdgcn_mfma_f32_32x32x16_bf16(alo, bhi, c, 0, 0, 0);
  }
#pragma unroll
  for (int r = 0; r < 16; ++r) {
    int row = tt * 32 + (r & 3) + 8 * (r >> 2) + 4 * h;
    DHs[row * 72 + n] = (__bf16)c[r];
  }
  __syncthreads();
#pragma unroll
  for (int r = 0; r < 2; ++r) {
    int idx = r * 256 + tid;
    int g = idx >> 8, cc = (idx >> 5) & 7, l = idx & 31;
    bf16x8 w = *(const bf16x8*)&DHs[(g * 32 + l) * 72 + cc * 8];
    *(bf16x8*)(DHf + (size_t)(blockIdx.x * 2 + g) * 2048 + cc * 256 + l * 8) = w;
  }
  if (tid < 64) {
    float s = 0.f;
#pragma unroll
    for (int q = 0; q < 8; ++q) {
      bf16x8 w = *(const bf16x8*)&DHs[tid * 72 + q * 8];
#pragma unroll
      for (int i = 0; i < 8; ++i) { float f = (float)w[i]; s += f * f; }
    }
    lbe[t0 + tid] = -0.5f * s * LOG2E;
    rowsum[t0 + tid] = 0.f;
  }
}

// ---------------------------------------------------------------------------
// K2: rowsum[t] += sum_j exp(S+lb). grid 2048 x 256.
//     Changes: 4 blocks/CU, full unroll + b-prefetch, split MFMA chains.
// ---------------------------------------------------------------------------
__global__ __launch_bounds__(256, 4) void k_rowsum(const __bf16* __restrict__ DHf,
                                                   const float* __restrict__ lbe,
                                                   float* __restrict__ rowsum) {
  __shared__ float red2[64 * 65];
  const int tid = threadIdx.x;
  const int lane = tid & 63;
  const int wave = tid >> 6;
  const int h = lane >> 5;
  const int tt = wave & 1, jt = wave >> 1;
  const int t0 = (int)(blockIdx.x >> 4) * 64;
  const int jbase = (int)(blockIdx.x & 15) * 512;
  const int Gt = (t0 >> 5) + tt;
  bf16x8 aR[4];
#pragma unroll
  for (int kk = 0; kk < 4; ++kk)
    aR[kk] = *(const bf16x8*)(DHf + (size_t)Gt * 2048 + kk * 512 + lane * 8);
  float racc[16];
#pragma unroll
  for (int r = 0; r < 16; ++r) racc[r] = 0.f;
  bf16x8 b[4];
  {
    const size_t Gj = (size_t)(jbase >> 5) + jt;
#pragma unroll
    for (int kk = 0; kk < 4; ++kk)
      b[kk] = *(const bf16x8*)(DHf + Gj * 2048 + kk * 512 + lane * 8);
  }
#pragma unroll
  for (int jit = 0; jit < 8; ++jit) {
    bf16x8 bn[4];
    if (jit < 7) {
      const size_t Gj = (size_t)(jbase >> 5) + (jit + 1) * 2 + jt;
#pragma unroll
      for (int kk = 0; kk < 4; ++kk)
        bn[kk] = *(const bf16x8*)(DHf + Gj * 2048 + kk * 512 + lane * 8);
    }
    const float lbv = lbe[jbase + jit * 64 + jt * 32 + (lane & 31)];
    f32x16 s0 = zero16(), s1 = zero16();
    s0 = __builtin_amdgcn_mfma_f32_32x32x16_bf16(aR[0], b[0], s0, 0, 0, 0);
    s1 = __builtin_amdgcn_mfma_f32_32x32x16_bf16(aR[1], b[1], s1, 0, 0, 0);
    s0 = __builtin_amdgcn_mfma_f32_32x32x16_bf16(aR[2], b[2], s0, 0, 0, 0);
    s1 = __builtin_amdgcn_mfma_f32_32x32x16_bf16(aR[3], b[3], s1, 0, 0, 0);
#pragma unroll
    for (int r = 0; r < 16; ++r)
      racc[r] += __builtin_amdgcn_exp2f(
          __builtin_fmaf(s0[r] + s1[r], LOG2E, lbv));
    if (jit < 7) {
#pragma unroll
      for (int kk = 0; kk < 4; ++kk) b[kk] = bn[kk];
    }
  }
#pragma unroll
  for (int r = 0; r < 16; ++r) {
    int tl = tt * 32 + (r & 3) + 8 * (r >> 2) + 4 * h;
    red2[tl * 65 + jt * 32 + (lane & 31)] = racc[r];
  }
  __syncthreads();
  if (tid < 64) {
    float s = 0.f;
#pragma unroll 8
    for (int c = 0; c < 64; ++c) s += red2[tid * 65 + c];
    atomicAdd(&rowsum[t0 + tid], s);
  }
}

// ---------------------------------------------------------------------------
// K2b: Hbf = bf16(H*rinv[t]) in CHUNK-MAJOR layout:
//      Hbf[tblk32][c=0..3][d=0..255][e=0..7], elem = H'[d][tblk*32+c*8+e].
//      This makes k_z's LDS image contiguous per lane-group -> no swizzle,
//      no bank conflicts. grid 256 x 256 (one t32-block per block).
// ---------------------------------------------------------------------------
__global__ __launch_bounds__(256) void k_scaleH(const float* __restrict__ H,
                                                const float* __restrict__ rowsum,
                                                __bf16* __restrict__ Hbf,
                                                float* __restrict__ Z,
                                                int zeroZ) {
  __shared__ float rinvL[32];
  const int tid = threadIdx.x;
  const int tblk = blockIdx.x;
  const int t0 = tblk * 32;
  if (tid < 32) rinvL[tid] = 1.0f / rowsum[t0 + tid];
  __syncthreads();
  const int d = tid;
  const float4* hp = (const float4*)(H + (size_t)d * T_DIM + t0);
#pragma unroll
  for (int c = 0; c < 4; ++c) {
    float4 v0 = hp[c * 2], v1 = hp[c * 2 + 1];
    const float4 r0 = *(const float4*)&rinvL[c * 8];
    const float4 r1 = *(const float4*)&rinvL[c * 8 + 4];
    bf16x8 w;
    w[0] = (__bf16)(v0.x * r0.x); w[1] = (__bf16)(v0.y * r0.y);
    w[2] = (__bf16)(v0.z * r0.z); w[3] = (__bf16)(v0.w * r0.w);
    w[4] = (__bf16)(v1.x * r1.x); w[5] = (__bf16)(v1.y * r1.y);
    w[6] = (__bf16)(v1.z * r1.z); w[7] = (__bf16)(v1.w * r1.w);
    *(bf16x8*)(Hbf + (size_t)tblk * 8192 + c * 2048 + d * 8) = w;
  }
  if (zeroZ) {
    float4* Z4 = (float4*)Z;
    const float4 z4 = {0.f, 0.f, 0.f, 0.f};
    const int base = blockIdx.x * 256 + tid;
#pragma unroll
    for (int r = 0; r < 8; ++r) Z4[r * 65536 + base] = z4;
  }
}

// ---------------------------------------------------------------------------
// K3: Zp[ts][d][j] = sum_{t in slice} H'[d][t]*E[t][j]  (or atomic into Z).
//     512 thr (8 waves), FULL d=256 (no dh dup -> exps halved), j-tile 128,
//     t32 per iter, ts=bx&7 (same-CU blocks share the H' tile stream).
//     LDS 48 KB chunk-major (conflict-free reads), 2 blocks/CU = 16 waves/CU.
//     One barrier/iter; DMA + aR prefetch in flight across it.
// ---------------------------------------------------------------------------
__global__ __launch_bounds__(512, 4) void k_z(const __bf16* __restrict__ Hbf,
                                              const __bf16* __restrict__ DHf,
                                              const float* __restrict__ lbe,
                                              const float* __restrict__ l2p,
                                              float* __restrict__ Z,
                                              float* __restrict__ Zp,
                                              int useAtomic) {
  __shared__ __bf16 Hs[2][4][256][8];  // 32 KB: H' tile, chunk-major
  __shared__ __bf16 Pt[2][4][128][8];  // 16 KB: E^T tile, chunk-major
  const int tid = threadIdx.x;
  const int lane = tid & 63;
  const int wave = tid >> 6;
  const int h = lane >> 5;
  const int l31 = lane & 31;
  const int bx = blockIdx.x;
  const int ts = bx & 7;               // t-slice id; matches XCD round-robin
  const int j0 = (bx >> 3) * 128;
  const int jh = wave & 3, kh = wave >> 2;  // S roles: j32-group, r-half
  const int dq = wave & 3, jv = wave >> 2;  // Z roles: d64-group, j64-half
  const int tb0 = ts * 32;             // first t32-block of this slice
  const float l2v = l2p[0];
  bf16x8 bS[4];
  {
    const size_t Gj = (size_t)(j0 >> 5) + jh;
#pragma unroll
    for (int kk = 0; kk < 4; ++kk)
      bS[kk] = *(const bf16x8*)(DHf + Gj * 2048 + kk * 512 + lane * 8);
  }
  const float lbv = lbe[j0 + jh * 32 + l31];
  f32x16 acc[2][2];
#pragma unroll
  for (int u = 0; u < 2; ++u)
#pragma unroll
    for (int v = 0; v < 2; ++v) acc[u][v] = zero16();

#define DMA_HS(buf_, it_)                                                       \
  {                                                                             \
    const __bf16* gsrc = Hbf + (size_t)(tb0 + (it_)) * 8192;                    \
    _Pragma("unroll") for (int r = 0; r < 2; ++r) {                             \
      const int slot = r * 512 + tid;                                           \
      __builtin_amdgcn_global_load_lds(                                         \
          (const __attribute__((address_space(1))) unsigned int*)(gsrc +        \
              slot * 8),                                                        \
          (__attribute__((address_space(3))) unsigned int*)(                    \
              &Hs[buf_][0][0][0] + slot * 8),                                   \
          16, 0, 0);                                                            \
    }                                                                           \
  }

#define LOAD_AR(it_)                                                            \
  {                                                                             \
    const size_t Gt_ = (size_t)(tb0 + (it_));                                   \
    _Pragma("unroll") for (int kk = 0; kk < 4; ++kk)                            \
        aR[kk] = *(const bf16x8*)(DHf + Gt_ * 2048 + kk * 512 + lane * 8);      \
  }

  // S tile t32 x j128: wave pair (kh) duplicates the 4 MFMAs, splits the exps.
#define S_PHASE(p_)                                                             \
  {                                                                             \
    f32x16 s0_ = zero16(), s1_ = zero16();                                      \
    s0_ = __builtin_amdgcn_mfma_f32_32x32x16_bf16(aR[0], bS[0], s0_, 0, 0, 0);  \
    s1_ = __builtin_amdgcn_mfma_f32_32x32x16_bf16(aR[1], bS[1], s1_, 0, 0, 0);  \
    s0_ = __builtin_amdgcn_mfma_f32_32x32x16_bf16(aR[2], bS[2], s0_, 0, 0, 0);  \
    s1_ = __builtin_amdgcn_mfma_f32_32x32x16_bf16(aR[3], bS[3], s1_, 0, 0, 0);  \
    const int jl_ = jh * 32 + l31;                                              \
    _Pragma("unroll") for (int g2 = 0; g2 < 2; ++g2) {                          \
      const int g_ = kh * 2 + g2;                                               \
      const int r_ = g_ * 4;                                                    \
      bf16x4 pv_;                                                               \
      pv_[0] = (__bf16)__builtin_amdgcn_exp2f(                                  \
          __builtin_fmaf(s0_[r_ + 0] + s1_[r_ + 0], LOG2E, lbv));               \
      pv_[1] = (__bf16)__builtin_amdgcn_exp2f(                                  \
          __builtin_fmaf(s0_[r_ + 1] + s1_[r_ + 1], LOG2E, lbv));               \
      pv_[2] = (__bf16)__builtin_amdgcn_exp2f(                                  \
          __builtin_fmaf(s0_[r_ + 2] + s1_[r_ + 2], LOG2E, lbv));               \
      pv_[3] = (__bf16)__builtin_amdgcn_exp2f(                                  \
          __builtin_fmaf(s0_[r_ + 3] + s1_[r_ + 3], LOG2E, lbv));               \
      *(bf16x4*)(&Pt[p_][g_][jl_][4 * h]) = pv_;                                \
    }                                                                           \
  }

  bf16x8 aR[4];
  LOAD_AR(0);
  DMA_HS(0, 0);
  S_PHASE(0);
  LOAD_AR(1);
  __syncthreads();  // Hs[0] drained, Pt[0] visible

  for (int it = 0; it < 32; ++it) {
    const int p = it & 1;
    if (it < 31) {
      DMA_HS(p ^ 1, it + 1);
      S_PHASE(p ^ 1);  // consumes aR = frags(it+1)
    }
    if (it < 30) LOAD_AR(it + 2);
    // ---- Z phase from buffers p ----
#pragma unroll
    for (int kk = 0; kk < 2; ++kk) {
      const int c = kk * 2 + h;
      bf16x8 af[2], bw[2];
#pragma unroll
      for (int u = 0; u < 2; ++u)
        af[u] = *(const bf16x8*)(&Hs[p][c][dq * 64 + u * 32 + l31][0]);
#pragma unroll
      for (int v = 0; v < 2; ++v)
        bw[v] = *(const bf16x8*)(&Pt[p][c][jv * 64 + v * 32 + l31][0]);
#pragma unroll
      for (int u = 0; u < 2; ++u)
#pragma unroll
        for (int v = 0; v < 2; ++v)
          acc[u][v] = __builtin_amdgcn_mfma_f32_32x32x16_bf16(af[u], bw[v],
                                                              acc[u][v], 0, 0, 0);
    }
    __syncthreads();  // one barrier/iter: next buffers ready, DMA drained
  }
#undef S_PHASE
#undef LOAD_AR
#undef DMA_HS
  // ---- epilogue: plain partial-plane stores (atomic fallback if ws small) ---
  if (useAtomic) {
#pragma unroll
    for (int u = 0; u < 2; ++u)
#pragma unroll
      for (int v = 0; v < 2; ++v)
#pragma unroll
        for (int r = 0; r < 16; ++r) {
          int d = dq * 64 + u * 32 + (r & 3) + 8 * (r >> 2) + 4 * h;
          int j = j0 + jv * 64 + v * 32 + l31;
          atomicAdd(&Z[(size_t)d * T_DIM + j], acc[u][v][r] * l2v);
        }
  } else {
    float* zp = Zp + (size_t)ts * (256 * (size_t)T_DIM);
#pragma unroll
    for (int u = 0; u < 2; ++u)
#pragma unroll
      for (int v = 0; v < 2; ++v)
#pragma unroll
        for (int r = 0; r < 16; ++r) {
          int d = dq * 64 + u * 32 + (r & 3) + 8 * (r >> 2) + 4 * h;
          int j = j0 + jv * 64 + v * 32 + l31;
          zp[(size_t)d * T_DIM + j] = acc[u][v][r];
        }
  }
}

// ---------------------------------------------------------------------------
// K4: Z = l2 * sum_{ts=0..7} Zp[ts]. grid 2048 x 256, pure HBM-bound.
// ---------------------------------------------------------------------------
__global__ __launch_bounds__(256) void k_zred(const float* __restrict__ Zp,
                                              const float* __restrict__ l2p,
                                              float* __restrict__ Z) {
  const int i = blockIdx.x * 256 + threadIdx.x;  // 524288 float4s total
  const float l2v = l2p[0];
  const float4* zp4 = (const float4*)Zp;
  float4 a = zp4[i];
#pragma unroll
  for (int s = 1; s < 8; ++s) {
    float4 b = zp4[(size_t)s * 524288 + i];
    a.x += b.x; a.y += b.y; a.z += b.z; a.w += b.w;
  }
  float4 o = {a.x * l2v, a.y * l2v, a.z * l2v, a.w * l2v};
  ((float4*)Z)[i] = o;
}

// ---------------------------------------------------------------------------
extern "C" void kernel_launch(void* const* d_in, const int* in_sizes, int n_in,
                              void* d_out, int out_size, void* d_ws,
                              size_t ws_size, hipStream_t stream) {
  (void)in_sizes; (void)n_in; (void)out_size;
  const float* H = (const float*)d_in[0];
  const float* Dm = (const float*)d_in[1];
  const float* l2 = (const float*)d_in[2];
  float* Z = (float*)d_out;
  char* ws = (char*)d_ws;
  __bf16* DHf = (__bf16*)ws;                        // 1,048,576 B
  float* lbe = (float*)(ws + 1048576);              // 32,768 B
  float* rowsum = (float*)(ws + 1048576 + 32768);   // 32,768 B
  __bf16* Hbf = (__bf16*)(ws + 1114112);            // 4,194,304 B (chunk-major)
  float* Zp = (float*)(ws + 5308416);               // 67,108,864 B (8 planes)
  const size_t need = 5308416ull + 67108864ull;
  const int usePartial = (ws_size >= need) ? 1 : 0;

  k_dh<<<128, 256, 0, stream>>>(H, Dm, DHf, lbe, rowsum);
  k_rowsum<<<2048, 256, 0, stream>>>(DHf, lbe, rowsum);
  k_scaleH<<<256, 256, 0, stream>>>(H, rowsum, Hbf, Z, usePartial ? 0 : 1);
  k_z<<<512, 512, 0, stream>>>(Hbf, DHf, lbe, l2, Z, Zp, usePartial ? 0 : 1);
  if (usePartial) k_zred<<<2048, 256, 0, stream>>>(Zp, l2, Z);
}

// Round 2
// 190.390 us; speedup vs baseline: 1.5235x; 1.5235x over previous
//
#include <hip/hip_runtime.h>

#define T_DIM 8192
#define D_DIM 256
#define N_DIM 64
#define LOG2E 1.44269504f

typedef __bf16 bf16x8 __attribute__((ext_vector_type(8)));
typedef __bf16 bf16x4 __attribute__((ext_vector_type(4)));
typedef float f32x16 __attribute__((ext_vector_type(16)));

__device__ __forceinline__ f32x16 zero16() {
  f32x16 v;
#pragma unroll
  for (int i = 0; i < 16; ++i) v[i] = 0.f;
  return v;
}

// DHf: fragment-major. Row-group G=t>>5, chunk c=kk*2+h, lane l31:
// DHf[G*2048 + c*256 + l31*8 .. +7] = DH[n=c*8+e][t=G*32+l31].

// ---------------------------------------------------------------------------
// K1: DHf (bf16, fragment-major) via split-bf16 MFMA, lbe[t]=lb*log2e,
//     rowsum[t]=0. grid 128 x 256.  (unchanged)
// ---------------------------------------------------------------------------
__global__ __launch_bounds__(256) void k_dh(const float* __restrict__ H,
                                            const float* __restrict__ Dm,
                                            __bf16* __restrict__ DHf,
                                            float* __restrict__ lbe,
                                            float* __restrict__ rowsum) {
  __shared__ __bf16 HlThi[64 * 264];
  __shared__ __bf16 HlTlo[64 * 264];
  __shared__ __bf16 DHs[64 * 72];
  const int tid = threadIdx.x;
  const int t0 = blockIdx.x * 64;
  const int lane = tid & 63;
  const int wave = tid >> 6;
  const int h = lane >> 5;
  const int l31 = lane & 31;
  const float4* H4 = (const float4*)H;
#pragma unroll
  for (int r = 0; r < 16; ++r) {
    int idx = r * 256 + tid;
    int d = idx >> 4, tc = idx & 15;
    float4 v = H4[(size_t)d * (T_DIM / 4) + (t0 >> 2) + tc];
    float vv[4] = {v.x, v.y, v.z, v.w};
#pragma unroll
    for (int i = 0; i < 4; ++i) {
      __bf16 hi = (__bf16)vv[i];
      float lo = vv[i] - (float)hi;
      HlThi[(tc * 4 + i) * 264 + d] = hi;
      HlTlo[(tc * 4 + i) * 264 + d] = (__bf16)lo;
    }
  }
  __syncthreads();
  const int tt = wave & 1, nh = wave >> 1;
  const int m = tt * 32 + l31;
  const int n = nh * 32 + l31;
  f32x16 c = zero16();
  for (int kk = 0; kk < 16; ++kk) {
    bf16x8 ahi = *(const bf16x8*)&HlThi[m * 264 + kk * 16 + h * 8];
    bf16x8 alo = *(const bf16x8*)&HlTlo[m * 264 + kk * 16 + h * 8];
    const float4* dp = (const float4*)(Dm + (size_t)n * 256 + kk * 16 + h * 8);
    float4 b0 = dp[0], b1 = dp[1];
    float bv[8] = {b0.x, b0.y, b0.z, b0.w, b1.x, b1.y, b1.z, b1.w};
    bf16x8 bhi, blo;
#pragma unroll
    for (int i = 0; i < 8; ++i) {
      __bf16 hi = (__bf16)bv[i];
      bhi[i] = hi;
      blo[i] = (__bf16)(bv[i] - (float)hi);
    }
    c = __builtin_amdgcn_mfma_f32_32x32x16_bf16(ahi, bhi, c, 0, 0, 0);
    c = __builtin_amdgcn_mfma_f32_32x32x16_bf16(ahi, blo, c, 0, 0, 0);
    c = __builtin_amdgcn_mfma_f32_32x32x16_bf16(alo, bhi, c, 0, 0, 0);
  }
#pragma unroll
  for (int r = 0; r < 16; ++r) {
    int row = tt * 32 + (r & 3) + 8 * (r >> 2) + 4 * h;
    DHs[row * 72 + n] = (__bf16)c[r];
  }
  __syncthreads();
#pragma unroll
  for (int r = 0; r < 2; ++r) {
    int idx = r * 256 + tid;
    int g = idx >> 8, cc = (idx >> 5) & 7, l = idx & 31;
    bf16x8 w = *(const bf16x8*)&DHs[(g * 32 + l) * 72 + cc * 8];
    *(bf16x8*)(DHf + (size_t)(blockIdx.x * 2 + g) * 2048 + cc * 256 + l * 8) = w;
  }
  if (tid < 64) {
    float s = 0.f;
#pragma unroll
    for (int q = 0; q < 8; ++q) {
      bf16x8 w = *(const bf16x8*)&DHs[tid * 72 + q * 8];
#pragma unroll
      for (int i = 0; i < 8; ++i) { float f = (float)w[i]; s += f * f; }
    }
    lbe[t0 + tid] = -0.5f * s * LOG2E;
    rowsum[t0 + tid] = 0.f;
  }
}

// ---------------------------------------------------------------------------
// K2: rowsum[t] += sum_j exp(S+lb). grid 2048 x 256.  (unchanged from R1)
// ---------------------------------------------------------------------------
__global__ __launch_bounds__(256, 4) void k_rowsum(const __bf16* __restrict__ DHf,
                                                   const float* __restrict__ lbe,
                                                   float* __restrict__ rowsum) {
  __shared__ float red2[64 * 65];
  const int tid = threadIdx.x;
  const int lane = tid & 63;
  const int wave = tid >> 6;
  const int h = lane >> 5;
  const int tt = wave & 1, jt = wave >> 1;
  const int t0 = (int)(blockIdx.x >> 4) * 64;
  const int jbase = (int)(blockIdx.x & 15) * 512;
  const int Gt = (t0 >> 5) + tt;
  bf16x8 aR[4];
#pragma unroll
  for (int kk = 0; kk < 4; ++kk)
    aR[kk] = *(const bf16x8*)(DHf + (size_t)Gt * 2048 + kk * 512 + lane * 8);
  float racc[16];
#pragma unroll
  for (int r = 0; r < 16; ++r) racc[r] = 0.f;
  bf16x8 b[4];
  {
    const size_t Gj = (size_t)(jbase >> 5) + jt;
#pragma unroll
    for (int kk = 0; kk < 4; ++kk)
      b[kk] = *(const bf16x8*)(DHf + Gj * 2048 + kk * 512 + lane * 8);
  }
#pragma unroll
  for (int jit = 0; jit < 8; ++jit) {
    bf16x8 bn[4];
    if (jit < 7) {
      const size_t Gj = (size_t)(jbase >> 5) + (jit + 1) * 2 + jt;
#pragma unroll
      for (int kk = 0; kk < 4; ++kk)
        bn[kk] = *(const bf16x8*)(DHf + Gj * 2048 + kk * 512 + lane * 8);
    }
    const float lbv = lbe[jbase + jit * 64 + jt * 32 + (lane & 31)];
    f32x16 s0 = zero16(), s1 = zero16();
    s0 = __builtin_amdgcn_mfma_f32_32x32x16_bf16(aR[0], b[0], s0, 0, 0, 0);
    s1 = __builtin_amdgcn_mfma_f32_32x32x16_bf16(aR[1], b[1], s1, 0, 0, 0);
    s0 = __builtin_amdgcn_mfma_f32_32x32x16_bf16(aR[2], b[2], s0, 0, 0, 0);
    s1 = __builtin_amdgcn_mfma_f32_32x32x16_bf16(aR[3], b[3], s1, 0, 0, 0);
#pragma unroll
    for (int r = 0; r < 16; ++r)
      racc[r] += __builtin_amdgcn_exp2f(
          __builtin_fmaf(s0[r] + s1[r], LOG2E, lbv));
    if (jit < 7) {
#pragma unroll
      for (int kk = 0; kk < 4; ++kk) b[kk] = bn[kk];
    }
  }
#pragma unroll
  for (int r = 0; r < 16; ++r) {
    int tl = tt * 32 + (r & 3) + 8 * (r >> 2) + 4 * h;
    red2[tl * 65 + jt * 32 + (lane & 31)] = racc[r];
  }
  __syncthreads();
  if (tid < 64) {
    float s = 0.f;
#pragma unroll 8
    for (int c = 0; c < 64; ++c) s += red2[tid * 65 + c];
    atomicAdd(&rowsum[t0 + tid], s);
  }
}

// ---------------------------------------------------------------------------
// K2b: Hbf = bf16(H*rinv[t]) in CHUNK-MAJOR layout:
//      Hbf[tblk32][c=0..3][d=0..255][e=0..7], elem = H'[d][tblk*32+c*8+e].
//      grid 256 x 256.  (unchanged from R1)
// ---------------------------------------------------------------------------
__global__ __launch_bounds__(256) void k_scaleH(const float* __restrict__ H,
                                                const float* __restrict__ rowsum,
                                                __bf16* __restrict__ Hbf,
                                                float* __restrict__ Z,
                                                int zeroZ) {
  __shared__ float rinvL[32];
  const int tid = threadIdx.x;
  const int tblk = blockIdx.x;
  const int t0 = tblk * 32;
  if (tid < 32) rinvL[tid] = 1.0f / rowsum[t0 + tid];
  __syncthreads();
  const int d = tid;
  const float4* hp = (const float4*)(H + (size_t)d * T_DIM + t0);
#pragma unroll
  for (int c = 0; c < 4; ++c) {
    float4 v0 = hp[c * 2], v1 = hp[c * 2 + 1];
    const float4 r0 = *(const float4*)&rinvL[c * 8];
    const float4 r1 = *(const float4*)&rinvL[c * 8 + 4];
    bf16x8 w;
    w[0] = (__bf16)(v0.x * r0.x); w[1] = (__bf16)(v0.y * r0.y);
    w[2] = (__bf16)(v0.z * r0.z); w[3] = (__bf16)(v0.w * r0.w);
    w[4] = (__bf16)(v1.x * r1.x); w[5] = (__bf16)(v1.y * r1.y);
    w[6] = (__bf16)(v1.z * r1.z); w[7] = (__bf16)(v1.w * r1.w);
    *(bf16x8*)(Hbf + (size_t)tblk * 8192 + c * 2048 + d * 8) = w;
  }
  if (zeroZ) {
    float4* Z4 = (float4*)Z;
    const float4 z4 = {0.f, 0.f, 0.f, 0.f};
    const int base = blockIdx.x * 256 + tid;
#pragma unroll
    for (int r = 0; r < 8; ++r) Z4[r * 65536 + base] = z4;
  }
}

// ---------------------------------------------------------------------------
// K3: Zp[ts][d][j] = sum_{t in slice} H'[d][t]*E[t][j]  (or atomic into Z).
//     512 thr (8 waves), full d=256, j-tile 64, t32/iter, 64 iters,
//     ts = bx&3 (2048-t slice; all blocks on an XCD share one Hbf slice).
//     REGISTER-BUDGETED for the 128-reg cap of __launch_bounds__(512,4):
//     per-lane peak = acc[2](32) + s(16) + aR(16) + bS(16) + temps ~= 96.
//     (R1 failure: acc[2][2]+s0/s1 = 145 regs -> AGPR+scratch spill,
//      VALUBusy 71%, 209us.)  LDS 40 KB chunk-major, conflict-free.
//     One barrier/iter; DMA + aR prefetch in flight across it.
// ---------------------------------------------------------------------------
__global__ __launch_bounds__(512, 4) void k_z(const __bf16* __restrict__ Hbf,
                                              const __bf16* __restrict__ DHf,
                                              const float* __restrict__ lbe,
                                              const float* __restrict__ l2p,
                                              float* __restrict__ Z,
                                              float* __restrict__ Zp,
                                              int useAtomic) {
  __shared__ __bf16 Hs[2][4][256][8];  // 32 KB: H' tile, chunk-major
  __shared__ __bf16 Pt[2][4][64][8];   //  8 KB: E^T tile, chunk-major
  const int tid = threadIdx.x;
  const int lane = tid & 63;
  const int wave = tid >> 6;
  const int h = lane >> 5;
  const int l31 = lane & 31;
  const int bx = blockIdx.x;
  const int ts = bx & 3;               // t-slice id == (XCD id & 3)
  const int j0 = (bx >> 2) * 64;
  const int jh = wave & 1, kh = wave >> 1;  // S roles: j32-group, row-octet
  const int dq = wave & 3, jv = wave >> 2;  // Z roles: d64-group, j32-group
  const int tb0 = ts * 64;             // first t32-block of this slice
  const float l2v = l2p[0];
  bf16x8 bS[4];
  {
    const size_t Gj = (size_t)(j0 >> 5) + jh;
#pragma unroll
    for (int kk = 0; kk < 4; ++kk)
      bS[kk] = *(const bf16x8*)(DHf + Gj * 2048 + kk * 512 + lane * 8);
  }
  const float lbv = lbe[j0 + jh * 32 + l31];
  f32x16 acc[2];
#pragma unroll
  for (int u = 0; u < 2; ++u) acc[u] = zero16();

#define DMA_HS(buf_, it_)                                                       \
  {                                                                             \
    const __bf16* gsrc = Hbf + (size_t)(tb0 + (it_)) * 8192;                    \
    _Pragma("unroll") for (int r = 0; r < 2; ++r) {                             \
      const int slot = r * 512 + tid;                                           \
      __builtin_amdgcn_global_load_lds(                                         \
          (const __attribute__((address_space(1))) unsigned int*)(gsrc +        \
              slot * 8),                                                        \
          (__attribute__((address_space(3))) unsigned int*)(                    \
              &Hs[buf_][0][0][0] + slot * 8),                                   \
          16, 0, 0);                                                            \
    }                                                                           \
  }

#define LOAD_AR(it_)                                                            \
  {                                                                             \
    const size_t Gt_ = (size_t)(tb0 + (it_));                                   \
    _Pragma("unroll") for (int kk = 0; kk < 4; ++kk)                            \
        aR[kk] = *(const bf16x8*)(DHf + Gt_ * 2048 + kk * 512 + lane * 8);      \
  }

  // S tile t32 x j64: 4 waves duplicate each j32-group's 4 MFMAs (kh splits
  // the 16 acc rows into octets) -> exps computed exactly once per (t,j).
#define S_PHASE(p_)                                                             \
  {                                                                             \
    f32x16 s_ = zero16();                                                       \
    s_ = __builtin_amdgcn_mfma_f32_32x32x16_bf16(aR[0], bS[0], s_, 0, 0, 0);    \
    s_ = __builtin_amdgcn_mfma_f32_32x32x16_bf16(aR[1], bS[1], s_, 0, 0, 0);    \
    s_ = __builtin_amdgcn_mfma_f32_32x32x16_bf16(aR[2], bS[2], s_, 0, 0, 0);    \
    s_ = __builtin_amdgcn_mfma_f32_32x32x16_bf16(aR[3], bS[3], s_, 0, 0, 0);    \
    const int jl_ = jh * 32 + l31;                                              \
    const int r_ = kh * 4;                                                      \
    bf16x4 pv_;                                                                 \
    pv_[0] = (__bf16)__builtin_amdgcn_exp2f(                                    \
        __builtin_fmaf(s_[r_ + 0], LOG2E, lbv));                                \
    pv_[1] = (__bf16)__builtin_amdgcn_exp2f(                                    \
        __builtin_fmaf(s_[r_ + 1], LOG2E, lbv));                                \
    pv_[2] = (__bf16)__builtin_amdgcn_exp2f(                                    \
        __builtin_fmaf(s_[r_ + 2], LOG2E, lbv));                                \
    pv_[3] = (__bf16)__builtin_amdgcn_exp2f(                                    \
        __builtin_fmaf(s_[r_ + 3], LOG2E, lbv));                                \
    *(bf16x4*)(&Pt[p_][kh][jl_][4 * h]) = pv_;                                  \
  }

  bf16x8 aR[4];
  LOAD_AR(0);
  DMA_HS(0, 0);
  S_PHASE(0);
  LOAD_AR(1);
  __syncthreads();  // Hs[0] drained, Pt[0] visible

  for (int it = 0; it < 64; ++it) {
    const int p = it & 1;
    if (it < 63) {
      DMA_HS(p ^ 1, it + 1);
      S_PHASE(p ^ 1);  // consumes aR = frags(it+1)
    }
    if (it < 62) LOAD_AR(it + 2);
    // ---- Z phase from buffers p ----
#pragma unroll
    for (int kk = 0; kk < 2; ++kk) {
      const int c = kk * 2 + h;
      bf16x8 af[2], bw;
#pragma unroll
      for (int u = 0; u < 2; ++u)
        af[u] = *(const bf16x8*)(&Hs[p][c][dq * 64 + u * 32 + l31][0]);
      bw = *(const bf16x8*)(&Pt[p][c][jv * 32 + l31][0]);
#pragma unroll
      for (int u = 0; u < 2; ++u)
        acc[u] = __builtin_amdgcn_mfma_f32_32x32x16_bf16(af[u], bw, acc[u],
                                                         0, 0, 0);
    }
    __syncthreads();  // one barrier/iter: next buffers ready, DMA drained
  }
#undef S_PHASE
#undef LOAD_AR
#undef DMA_HS
  // ---- epilogue: plain partial-plane stores (atomic fallback if ws small) ---
  if (useAtomic) {
#pragma unroll
    for (int u = 0; u < 2; ++u)
#pragma unroll
      for (int r = 0; r < 16; ++r) {
        int d = dq * 64 + u * 32 + (r & 3) + 8 * (r >> 2) + 4 * h;
        int j = j0 + jv * 32 + l31;
        atomicAdd(&Z[(size_t)d * T_DIM + j], acc[u][r] * l2v);
      }
  } else {
    float* zp = Zp + (size_t)ts * (256 * (size_t)T_DIM);
#pragma unroll
    for (int u = 0; u < 2; ++u)
#pragma unroll
      for (int r = 0; r < 16; ++r) {
        int d = dq * 64 + u * 32 + (r & 3) + 8 * (r >> 2) + 4 * h;
        int j = j0 + jv * 32 + l31;
        zp[(size_t)d * T_DIM + j] = acc[u][r];
      }
  }
}

// ---------------------------------------------------------------------------
// K4: Z = l2 * sum_{ts=0..3} Zp[ts]. grid 2048 x 256, pure HBM-bound (~40MB).
// ---------------------------------------------------------------------------
__global__ __launch_bounds__(256) void k_zred(const float* __restrict__ Zp,
                                              const float* __restrict__ l2p,
                                              float* __restrict__ Z) {
  const int i = blockIdx.x * 256 + threadIdx.x;  // 524288 float4s total
  const float l2v = l2p[0];
  const float4* zp4 = (const float4*)Zp;
  float4 a = zp4[i];
#pragma unroll
  for (int s = 1; s < 4; ++s) {
    float4 b = zp4[(size_t)s * 524288 + i];
    a.x += b.x; a.y += b.y; a.z += b.z; a.w += b.w;
  }
  float4 o = {a.x * l2v, a.y * l2v, a.z * l2v, a.w * l2v};
  ((float4*)Z)[i] = o;
}

// ---------------------------------------------------------------------------
extern "C" void kernel_launch(void* const* d_in, const int* in_sizes, int n_in,
                              void* d_out, int out_size, void* d_ws,
                              size_t ws_size, hipStream_t stream) {
  (void)in_sizes; (void)n_in; (void)out_size;
  const float* H = (const float*)d_in[0];
  const float* Dm = (const float*)d_in[1];
  const float* l2 = (const float*)d_in[2];
  float* Z = (float*)d_out;
  char* ws = (char*)d_ws;
  __bf16* DHf = (__bf16*)ws;                        // 1,048,576 B
  float* lbe = (float*)(ws + 1048576);              // 32,768 B
  float* rowsum = (float*)(ws + 1048576 + 32768);   // 32,768 B
  __bf16* Hbf = (__bf16*)(ws + 1114112);            // 4,194,304 B (chunk-major)
  float* Zp = (float*)(ws + 5308416);               // 33,554,432 B (4 planes)
  const size_t need = 5308416ull + 33554432ull;
  const int usePartial = (ws_size >= need) ? 1 : 0;

  k_dh<<<128, 256, 0, stream>>>(H, Dm, DHf, lbe, rowsum);
  k_rowsum<<<2048, 256, 0, stream>>>(DHf, lbe, rowsum);
  k_scaleH<<<256, 256, 0, stream>>>(H, rowsum, Hbf, Z, usePartial ? 0 : 1);
  k_z<<<512, 512, 0, stream>>>(Hbf, DHf, lbe, l2, Z, Zp, usePartial ? 0 : 1);
  if (usePartial) k_zred<<<2048, 256, 0, stream>>>(Zp, l2, Z);
}

// Round 3
// 159.727 us; speedup vs baseline: 1.8159x; 1.1920x over previous
//
#include <hip/hip_runtime.h>

#define T_DIM 8192
#define D_DIM 256
#define N_DIM 64
#define LOG2E 1.44269504f

typedef __bf16 bf16x8 __attribute__((ext_vector_type(8)));
typedef __bf16 bf16x4 __attribute__((ext_vector_type(4)));
typedef float f32x16 __attribute__((ext_vector_type(16)));

__device__ __forceinline__ f32x16 zero16() {
  f32x16 v;
#pragma unroll
  for (int i = 0; i < 16; ++i) v[i] = 0.f;
  return v;
}

// DHf: fragment-major. Row-group G=t>>5, chunk c=kk*2+h, lane l31:
// DHf[G*2048 + c*256 + l31*8 .. +7] = DH[n=c*8+e][t=G*32+l31].

// ---------------------------------------------------------------------------
// K1: DHf (bf16, fragment-major) via split-bf16 MFMA, lbe[t]=lb*log2e,
//     rowsum[t]=0. grid 128 x 256.  (unchanged)
// ---------------------------------------------------------------------------
__global__ __launch_bounds__(256) void k_dh(const float* __restrict__ H,
                                            const float* __restrict__ Dm,
                                            __bf16* __restrict__ DHf,
                                            float* __restrict__ lbe,
                                            float* __restrict__ rowsum) {
  __shared__ __bf16 HlThi[64 * 264];
  __shared__ __bf16 HlTlo[64 * 264];
  __shared__ __bf16 DHs[64 * 72];
  const int tid = threadIdx.x;
  const int t0 = blockIdx.x * 64;
  const int lane = tid & 63;
  const int wave = tid >> 6;
  const int h = lane >> 5;
  const int l31 = lane & 31;
  const float4* H4 = (const float4*)H;
#pragma unroll
  for (int r = 0; r < 16; ++r) {
    int idx = r * 256 + tid;
    int d = idx >> 4, tc = idx & 15;
    float4 v = H4[(size_t)d * (T_DIM / 4) + (t0 >> 2) + tc];
    float vv[4] = {v.x, v.y, v.z, v.w};
#pragma unroll
    for (int i = 0; i < 4; ++i) {
      __bf16 hi = (__bf16)vv[i];
      float lo = vv[i] - (float)hi;
      HlThi[(tc * 4 + i) * 264 + d] = hi;
      HlTlo[(tc * 4 + i) * 264 + d] = (__bf16)lo;
    }
  }
  __syncthreads();
  const int tt = wave & 1, nh = wave >> 1;
  const int m = tt * 32 + l31;
  const int n = nh * 32 + l31;
  f32x16 c = zero16();
  for (int kk = 0; kk < 16; ++kk) {
    bf16x8 ahi = *(const bf16x8*)&HlThi[m * 264 + kk * 16 + h * 8];
    bf16x8 alo = *(const bf16x8*)&HlTlo[m * 264 + kk * 16 + h * 8];
    const float4* dp = (const float4*)(Dm + (size_t)n * 256 + kk * 16 + h * 8);
    float4 b0 = dp[0], b1 = dp[1];
    float bv[8] = {b0.x, b0.y, b0.z, b0.w, b1.x, b1.y, b1.z, b1.w};
    bf16x8 bhi, blo;
#pragma unroll
    for (int i = 0; i < 8; ++i) {
      __bf16 hi = (__bf16)bv[i];
      bhi[i] = hi;
      blo[i] = (__bf16)(bv[i] - (float)hi);
    }
    c = __builtin_amdgcn_mfma_f32_32x32x16_bf16(ahi, bhi, c, 0, 0, 0);
    c = __builtin_amdgcn_mfma_f32_32x32x16_bf16(ahi, blo, c, 0, 0, 0);
    c = __builtin_amdgcn_mfma_f32_32x32x16_bf16(alo, bhi, c, 0, 0, 0);
  }
#pragma unroll
  for (int r = 0; r < 16; ++r) {
    int row = tt * 32 + (r & 3) + 8 * (r >> 2) + 4 * h;
    DHs[row * 72 + n] = (__bf16)c[r];
  }
  __syncthreads();
#pragma unroll
  for (int r = 0; r < 2; ++r) {
    int idx = r * 256 + tid;
    int g = idx >> 8, cc = (idx >> 5) & 7, l = idx & 31;
    bf16x8 w = *(const bf16x8*)&DHs[(g * 32 + l) * 72 + cc * 8];
    *(bf16x8*)(DHf + (size_t)(blockIdx.x * 2 + g) * 2048 + cc * 256 + l * 8) = w;
  }
  if (tid < 64) {
    float s = 0.f;
#pragma unroll
    for (int q = 0; q < 8; ++q) {
      bf16x8 w = *(const bf16x8*)&DHs[tid * 72 + q * 8];
#pragma unroll
      for (int i = 0; i < 8; ++i) { float f = (float)w[i]; s += f * f; }
    }
    lbe[t0 + tid] = -0.5f * s * LOG2E;
    rowsum[t0 + tid] = 0.f;
  }
}

// ---------------------------------------------------------------------------
// K2 v3: rowsum[t] += sum_j exp(S+lb). grid 512 x 512 threads.
//     t-tile 256 (8 waves = 8 t-groups), j32 per iter, 16 iters (j-range 512).
//     DHf re-read volume: 32 t-blocks x ~1.5MB = ~49MB (was 262MB with t64
//     blocks) -- the L3-latency-bound re-stream was the hidden ~60us.
//     All 8 waves load the SAME B-frags per iter (L1 broadcast). Zero MFMA
//     duplication. Regs ~100 < 128 cap at (512,4) -> no spill.
// ---------------------------------------------------------------------------
__global__ __launch_bounds__(512, 4) void k_rowsum(const __bf16* __restrict__ DHf,
                                                   const float* __restrict__ lbe,
                                                   float* __restrict__ rowsum) {
  __shared__ float red2[256][33];  // 33.8 KB, conflict-free transpose
  const int tid = threadIdx.x;
  const int lane = tid & 63;
  const int wave = tid >> 6;  // 0..7 = t-group
  const int h = lane >> 5;
  const int l31 = lane & 31;
  const int t0 = (int)(blockIdx.x >> 4) * 256;     // 32 t-blocks
  const int jbase = (int)(blockIdx.x & 15) * 512;  // 16 j-splits
  const size_t Gt = (size_t)(t0 >> 5) + wave;
  bf16x8 aR[4];
#pragma unroll
  for (int kk = 0; kk < 4; ++kk)
    aR[kk] = *(const bf16x8*)(DHf + Gt * 2048 + kk * 512 + lane * 8);
  float racc[16];
#pragma unroll
  for (int r = 0; r < 16; ++r) racc[r] = 0.f;
  bf16x8 b[4];
  {
    const size_t Gj = (size_t)(jbase >> 5);
#pragma unroll
    for (int kk = 0; kk < 4; ++kk)
      b[kk] = *(const bf16x8*)(DHf + Gj * 2048 + kk * 512 + lane * 8);
  }
  for (int jit = 0; jit < 16; ++jit) {
    bf16x8 bn[4];
    if (jit < 15) {
      const size_t Gj = (size_t)(jbase >> 5) + jit + 1;
#pragma unroll
      for (int kk = 0; kk < 4; ++kk)
        bn[kk] = *(const bf16x8*)(DHf + Gj * 2048 + kk * 512 + lane * 8);
    }
    const float lbv = lbe[jbase + jit * 32 + l31];
    f32x16 s = zero16();
    s = __builtin_amdgcn_mfma_f32_32x32x16_bf16(aR[0], b[0], s, 0, 0, 0);
    s = __builtin_amdgcn_mfma_f32_32x32x16_bf16(aR[1], b[1], s, 0, 0, 0);
    s = __builtin_amdgcn_mfma_f32_32x32x16_bf16(aR[2], b[2], s, 0, 0, 0);
    s = __builtin_amdgcn_mfma_f32_32x32x16_bf16(aR[3], b[3], s, 0, 0, 0);
#pragma unroll
    for (int r = 0; r < 16; ++r)
      racc[r] += __builtin_amdgcn_exp2f(__builtin_fmaf(s[r], LOG2E, lbv));
    if (jit < 15) {
#pragma unroll
      for (int kk = 0; kk < 4; ++kk) b[kk] = bn[kk];
    }
  }
  // each (t) row is owned by exactly one wave: no cross-wave duplication
#pragma unroll
  for (int r = 0; r < 16; ++r) {
    int tl = wave * 32 + (r & 3) + 8 * (r >> 2) + 4 * h;
    red2[tl][l31] = racc[r];
  }
  __syncthreads();
  if (tid < 256) {
    float s = 0.f;
#pragma unroll 8
    for (int c = 0; c < 32; ++c) s += red2[tid][c];
    atomicAdd(&rowsum[t0 + tid], s);
  }
}

// ---------------------------------------------------------------------------
// K2b: Hbf_sw = bf16(H*rinv[t]) pre-swizzled to k_z's LDS image; zeroes Z.
//      grid 256 x 256.  (R0-proven swizzled-image version.)
// ---------------------------------------------------------------------------
__global__ __launch_bounds__(256) void k_scaleH(const float* __restrict__ H,
                                                const float* __restrict__ rowsum,
                                                __bf16* __restrict__ Hbf_sw,
                                                float* __restrict__ Z) {
  __shared__ float rinvL[64];
  const int tid = threadIdx.x;
  const int bx = blockIdx.x;
  const int tblk = bx >> 1, dh = bx & 1;
  const int t0 = tblk * 64;
  if (tid < 64) rinvL[tid] = 1.0f / rowsum[t0 + tid];
  __syncthreads();
#pragma unroll
  for (int itr = 0; itr < 4; ++itr) {
    int idx = itr * 256 + tid;
    int dl = idx >> 3, tbp = idx & 7;
    int d = dh * 128 + dl;
    int swz = (d ^ (d >> 3)) & 7;
    int tloc = (tbp ^ swz) << 3;
    const float4* hp = (const float4*)(H + (size_t)d * T_DIM + t0 + tloc);
    float4 v0 = hp[0], v1 = hp[1];
    float4 r0 = *(const float4*)&rinvL[tloc];
    float4 r1 = *(const float4*)&rinvL[tloc + 4];
    bf16x8 w;
    w[0] = (__bf16)(v0.x * r0.x); w[1] = (__bf16)(v0.y * r0.y);
    w[2] = (__bf16)(v0.z * r0.z); w[3] = (__bf16)(v0.w * r0.w);
    w[4] = (__bf16)(v1.x * r1.x); w[5] = (__bf16)(v1.y * r1.y);
    w[6] = (__bf16)(v1.z * r1.z); w[7] = (__bf16)(v1.w * r1.w);
    *(bf16x8*)(Hbf_sw + (size_t)tblk * 16384 + (size_t)d * 64 + tbp * 8) = w;
  }
  float4* Z4 = (float4*)Z;
  const int base = bx * 256 + tid;
  const float4 z4 = {0.f, 0.f, 0.f, 0.f};
#pragma unroll
  for (int r = 0; r < 8; ++r) Z4[r * 65536 + base] = z4;
}

// ---------------------------------------------------------------------------
// K3: Z[d][j] += l2 * sum_t H'[d][t] * E[t][j].
//     grid 512 = 64 j-tiles(128) x 2 d-halves(128) x 4 t-splits(2048).
//     R0-proven version (77.5us): Hs AND Pt double-buffered (64 KB LDS),
//     ONE barrier per t64-iter, DMA in flight across the barrier, 2 blk/CU.
// ---------------------------------------------------------------------------
__global__ __launch_bounds__(256, 2) void k_z(const __bf16* __restrict__ Hbf_sw,
                                              const __bf16* __restrict__ DHf,
                                              const float* __restrict__ lbe,
                                              const float* __restrict__ l2p,
                                              float* __restrict__ Z) {
  __shared__ __bf16 Hs[2][128 * 64];  // [dl][t] swizzled, 2 x 16 KB
  __shared__ __bf16 Pt[2][128 * 64];  // [j][t] swizzled,  2 x 16 KB
  const int tid = threadIdx.x;
  const int lane = tid & 63;
  const int wave = tid >> 6;
  const int h = lane >> 5;
  const int l31 = lane & 31;
  const int bx = blockIdx.x;
  const int ts = bx & 3;
  const int dh = (bx >> 2) & 1;
  const int j0 = (bx >> 3) * 128;
  const float l2v = l2p[0];
  const int s_tt = wave & 1, s_jg = wave >> 1;
  // resident S-phase B fragments + lbe
  bf16x8 bS[2][4];
  float lbv[2];
#pragma unroll
  for (int q = 0; q < 2; ++q) {
    const size_t Gj = (j0 >> 5) + s_jg * 2 + q;
#pragma unroll
    for (int kk = 0; kk < 4; ++kk)
      bS[q][kk] = *(const bf16x8*)(DHf + Gj * 2048 + kk * 512 + lane * 8);
    lbv[q] = lbe[j0 + (s_jg * 2 + q) * 32 + l31];
  }
  f32x16 acc[2][2];
#pragma unroll
  for (int u = 0; u < 2; ++u)
#pragma unroll
    for (int v = 0; v < 2; ++v) acc[u][v] = zero16();

  // DMA of H' tile 'it_' into Hs[buf_]
#define DMA_HS(buf_, it_)                                                       \
  {                                                                             \
    const __bf16* gsrc =                                                        \
        Hbf_sw + (size_t)(ts * 32 + (it_)) * 16384 + (size_t)dh * 8192;         \
    _Pragma("unroll") for (int r = 0; r < 4; ++r) {                             \
      int chunk = wave * 4 + r;                                                 \
      __builtin_amdgcn_global_load_lds(                                         \
          (const __attribute__((address_space(1))) unsigned int*)(gsrc +        \
              chunk * 512 + lane * 8),                                          \
          (__attribute__((address_space(3))) unsigned int*)(&Hs[buf_][0] +      \
              chunk * 512),                                                     \
          16, 0, 0);                                                            \
    }                                                                           \
  }

  // S-phase into Pt[p_] using current aR
#define S_PHASE(p_)                                                             \
  {                                                                             \
    _Pragma("unroll") for (int q = 0; q < 2; ++q) {                             \
      f32x16 s = zero16();                                                      \
      _Pragma("unroll") for (int kk = 0; kk < 4; ++kk)                          \
          s = __builtin_amdgcn_mfma_f32_32x32x16_bf16(aR[kk], bS[q][kk], s, 0,  \
                                                      0, 0);                    \
      const int jl = (s_jg * 2 + q) * 32 + l31;                                 \
      const int sj = (jl ^ (jl >> 3)) & 7;                                      \
      _Pragma("unroll") for (int g = 0; g < 4; ++g) {                           \
        const int tl = s_tt * 32 + g * 8 + 4 * h;                               \
        bf16x4 pv;                                                              \
        pv[0] = (__bf16)__builtin_amdgcn_exp2f(                                 \
            __builtin_fmaf(s[g * 4 + 0], LOG2E, lbv[q]));                       \
        pv[1] = (__bf16)__builtin_amdgcn_exp2f(                                 \
            __builtin_fmaf(s[g * 4 + 1], LOG2E, lbv[q]));                       \
        pv[2] = (__bf16)__builtin_amdgcn_exp2f(                                 \
            __builtin_fmaf(s[g * 4 + 2], LOG2E, lbv[q]));                       \
        pv[3] = (__bf16)__builtin_amdgcn_exp2f(                                 \
            __builtin_fmaf(s[g * 4 + 3], LOG2E, lbv[q]));                       \
        const int cchunk = tl >> 3;                                             \
        *(bf16x4*)&Pt[p_][jl * 64 + ((cchunk ^ sj) << 3) + 4 * h] = pv;         \
      }                                                                         \
    }                                                                           \
  }

  bf16x8 aR[4];
#pragma unroll
  for (int kk = 0; kk < 4; ++kk)  // A frags for it=0
    aR[kk] = *(const bf16x8*)(DHf + (size_t)(ts * 64 + s_tt) * 2048 + kk * 512 + lane * 8);
  // prologue: DMA Hs[0] (it=0), compute Pt[0] (it=0), prefetch aR(it=1)
  DMA_HS(0, 0);
  S_PHASE(0);
#pragma unroll
  for (int kk = 0; kk < 4; ++kk)
    aR[kk] = *(const bf16x8*)(DHf + (size_t)(ts * 64 + 2 + s_tt) * 2048 + kk * 512 + lane * 8);
  __syncthreads();  // Hs[0] drained, Pt[0] visible

  for (int it = 0; it < 32; ++it) {
    const int p = it & 1;
    // issue next tile's DMA + S-phase first (drain deferred to iter-end barrier)
    if (it < 31) {
      DMA_HS(p ^ 1, it + 1);
      S_PHASE(p ^ 1);  // consumes aR = frags(it+1)
    }
    if (it < 30) {
      const size_t Gt = ts * 64 + (it + 2) * 2 + s_tt;
#pragma unroll
      for (int kk = 0; kk < 4; ++kk)
        aR[kk] = *(const bf16x8*)(DHf + Gt * 2048 + kk * 512 + lane * 8);
    }
    // ---- Z phase from buffers p ----
#pragma unroll
    for (int kk = 0; kk < 4; ++kk) {
      const int c = kk * 2 + h;
      bf16x8 af[2], bw[2];
#pragma unroll
      for (int u = 0; u < 2; ++u) {
        int dl = (wave & 1) * 64 + u * 32 + l31;
        af[u] = *(const bf16x8*)&Hs[p][dl * 64 + ((c ^ ((dl ^ (dl >> 3)) & 7)) << 3)];
      }
#pragma unroll
      for (int v = 0; v < 2; ++v) {
        int j = (wave >> 1) * 64 + v * 32 + l31;
        bw[v] = *(const bf16x8*)&Pt[p][j * 64 + ((c ^ ((j ^ (j >> 3)) & 7)) << 3)];
      }
#pragma unroll
      for (int u = 0; u < 2; ++u)
#pragma unroll
        for (int v = 0; v < 2; ++v)
          acc[u][v] = __builtin_amdgcn_mfma_f32_32x32x16_bf16(af[u], bw[v], acc[u][v], 0, 0, 0);
    }
    __syncthreads();  // one barrier/iter: next buffers ready, DMA drained
  }
#undef S_PHASE
#undef DMA_HS
  // ---- epilogue ----
#pragma unroll
  for (int u = 0; u < 2; ++u)
#pragma unroll
    for (int v = 0; v < 2; ++v)
#pragma unroll
      for (int r = 0; r < 16; ++r) {
        int d = dh * 128 + (wave & 1) * 64 + u * 32 + (r & 3) + 8 * (r >> 2) + 4 * h;
        int j = j0 + (wave >> 1) * 64 + v * 32 + l31;
        atomicAdd(&Z[(size_t)d * T_DIM + j], acc[u][v][r] * l2v);
      }
}

// ---------------------------------------------------------------------------
extern "C" void kernel_launch(void* const* d_in, const int* in_sizes, int n_in,
                              void* d_out, int out_size, void* d_ws,
                              size_t ws_size, hipStream_t stream) {
  (void)in_sizes; (void)n_in; (void)out_size; (void)ws_size;
  const float* H = (const float*)d_in[0];
  const float* Dm = (const float*)d_in[1];
  const float* l2 = (const float*)d_in[2];
  float* Z = (float*)d_out;
  char* ws = (char*)d_ws;
  __bf16* DHf = (__bf16*)ws;                        // 1,048,576 B
  float* lbe = (float*)(ws + 1048576);              // 32,768 B
  float* rowsum = (float*)(ws + 1048576 + 32768);   // 32,768 B
  __bf16* Hbf_sw = (__bf16*)(ws + 1048576 + 65536); // 4,194,304 B

  k_dh<<<128, 256, 0, stream>>>(H, Dm, DHf, lbe, rowsum);
  k_rowsum<<<512, 512, 0, stream>>>(DHf, lbe, rowsum);
  k_scaleH<<<256, 256, 0, stream>>>(H, rowsum, Hbf_sw, Z);
  k_z<<<512, 256, 0, stream>>>(Hbf_sw, DHf, lbe, l2, Z);
}

// Round 4
// 145.696 us; speedup vs baseline: 1.9908x; 1.0963x over previous
//
#include <hip/hip_runtime.h>

#define T_DIM 8192
#define D_DIM 256
#define N_DIM 64
#define LOG2E 1.44269504f

typedef __bf16 bf16x8 __attribute__((ext_vector_type(8)));
typedef __bf16 bf16x4 __attribute__((ext_vector_type(4)));
typedef float f32x16 __attribute__((ext_vector_type(16)));

__device__ __forceinline__ f32x16 zero16() {
  f32x16 v;
#pragma unroll
  for (int i = 0; i < 16; ++i) v[i] = 0.f;
  return v;
}

// DHf: fragment-major. Row-group G=t>>5, chunk c=kk*2+h, lane l31:
// DHf[G*2048 + c*256 + l31*8 .. +7] = DH[n=c*8+e][t=G*32+l31].

// ---------------------------------------------------------------------------
// K1: DHf (bf16, fragment-major) via split-bf16 MFMA, lbe[t]=lb*log2e,
//     rowsum[t]=0. grid 128 x 256.  (unchanged)
// ---------------------------------------------------------------------------
__global__ __launch_bounds__(256) void k_dh(const float* __restrict__ H,
                                            const float* __restrict__ Dm,
                                            __bf16* __restrict__ DHf,
                                            float* __restrict__ lbe,
                                            float* __restrict__ rowsum) {
  __shared__ __bf16 HlThi[64 * 264];
  __shared__ __bf16 HlTlo[64 * 264];
  __shared__ __bf16 DHs[64 * 72];
  const int tid = threadIdx.x;
  const int t0 = blockIdx.x * 64;
  const int lane = tid & 63;
  const int wave = tid >> 6;
  const int h = lane >> 5;
  const int l31 = lane & 31;
  const float4* H4 = (const float4*)H;
#pragma unroll
  for (int r = 0; r < 16; ++r) {
    int idx = r * 256 + tid;
    int d = idx >> 4, tc = idx & 15;
    float4 v = H4[(size_t)d * (T_DIM / 4) + (t0 >> 2) + tc];
    float vv[4] = {v.x, v.y, v.z, v.w};
#pragma unroll
    for (int i = 0; i < 4; ++i) {
      __bf16 hi = (__bf16)vv[i];
      float lo = vv[i] - (float)hi;
      HlThi[(tc * 4 + i) * 264 + d] = hi;
      HlTlo[(tc * 4 + i) * 264 + d] = (__bf16)lo;
    }
  }
  __syncthreads();
  const int tt = wave & 1, nh = wave >> 1;
  const int m = tt * 32 + l31;
  const int n = nh * 32 + l31;
  f32x16 c = zero16();
  for (int kk = 0; kk < 16; ++kk) {
    bf16x8 ahi = *(const bf16x8*)&HlThi[m * 264 + kk * 16 + h * 8];
    bf16x8 alo = *(const bf16x8*)&HlTlo[m * 264 + kk * 16 + h * 8];
    const float4* dp = (const float4*)(Dm + (size_t)n * 256 + kk * 16 + h * 8);
    float4 b0 = dp[0], b1 = dp[1];
    float bv[8] = {b0.x, b0.y, b0.z, b0.w, b1.x, b1.y, b1.z, b1.w};
    bf16x8 bhi, blo;
#pragma unroll
    for (int i = 0; i < 8; ++i) {
      __bf16 hi = (__bf16)bv[i];
      bhi[i] = hi;
      blo[i] = (__bf16)(bv[i] - (float)hi);
    }
    c = __builtin_amdgcn_mfma_f32_32x32x16_bf16(ahi, bhi, c, 0, 0, 0);
    c = __builtin_amdgcn_mfma_f32_32x32x16_bf16(ahi, blo, c, 0, 0, 0);
    c = __builtin_amdgcn_mfma_f32_32x32x16_bf16(alo, bhi, c, 0, 0, 0);
  }
#pragma unroll
  for (int r = 0; r < 16; ++r) {
    int row = tt * 32 + (r & 3) + 8 * (r >> 2) + 4 * h;
    DHs[row * 72 + n] = (__bf16)c[r];
  }
  __syncthreads();
#pragma unroll
  for (int r = 0; r < 2; ++r) {
    int idx = r * 256 + tid;
    int g = idx >> 8, cc = (idx >> 5) & 7, l = idx & 31;
    bf16x8 w = *(const bf16x8*)&DHs[(g * 32 + l) * 72 + cc * 8];
    *(bf16x8*)(DHf + (size_t)(blockIdx.x * 2 + g) * 2048 + cc * 256 + l * 8) = w;
  }
  if (tid < 64) {
    float s = 0.f;
#pragma unroll
    for (int q = 0; q < 8; ++q) {
      bf16x8 w = *(const bf16x8*)&DHs[tid * 72 + q * 8];
#pragma unroll
      for (int i = 0; i < 8; ++i) { float f = (float)w[i]; s += f * f; }
    }
    lbe[t0 + tid] = -0.5f * s * LOG2E;
    rowsum[t0 + tid] = 0.f;
  }
}

// ---------------------------------------------------------------------------
// K2 v3: rowsum[t] += sum_j exp(S+lb). grid 512 x 512 threads. (unchanged)
// ---------------------------------------------------------------------------
__global__ __launch_bounds__(512, 4) void k_rowsum(const __bf16* __restrict__ DHf,
                                                   const float* __restrict__ lbe,
                                                   float* __restrict__ rowsum) {
  __shared__ float red2[256][33];
  const int tid = threadIdx.x;
  const int lane = tid & 63;
  const int wave = tid >> 6;
  const int h = lane >> 5;
  const int l31 = lane & 31;
  const int t0 = (int)(blockIdx.x >> 4) * 256;
  const int jbase = (int)(blockIdx.x & 15) * 512;
  const size_t Gt = (size_t)(t0 >> 5) + wave;
  bf16x8 aR[4];
#pragma unroll
  for (int kk = 0; kk < 4; ++kk)
    aR[kk] = *(const bf16x8*)(DHf + Gt * 2048 + kk * 512 + lane * 8);
  float racc[16];
#pragma unroll
  for (int r = 0; r < 16; ++r) racc[r] = 0.f;
  bf16x8 b[4];
  {
    const size_t Gj = (size_t)(jbase >> 5);
#pragma unroll
    for (int kk = 0; kk < 4; ++kk)
      b[kk] = *(const bf16x8*)(DHf + Gj * 2048 + kk * 512 + lane * 8);
  }
  for (int jit = 0; jit < 16; ++jit) {
    bf16x8 bn[4];
    if (jit < 15) {
      const size_t Gj = (size_t)(jbase >> 5) + jit + 1;
#pragma unroll
      for (int kk = 0; kk < 4; ++kk)
        bn[kk] = *(const bf16x8*)(DHf + Gj * 2048 + kk * 512 + lane * 8);
    }
    const float lbv = lbe[jbase + jit * 32 + l31];
    f32x16 s = zero16();
    s = __builtin_amdgcn_mfma_f32_32x32x16_bf16(aR[0], b[0], s, 0, 0, 0);
    s = __builtin_amdgcn_mfma_f32_32x32x16_bf16(aR[1], b[1], s, 0, 0, 0);
    s = __builtin_amdgcn_mfma_f32_32x32x16_bf16(aR[2], b[2], s, 0, 0, 0);
    s = __builtin_amdgcn_mfma_f32_32x32x16_bf16(aR[3], b[3], s, 0, 0, 0);
#pragma unroll
    for (int r = 0; r < 16; ++r)
      racc[r] += __builtin_amdgcn_exp2f(__builtin_fmaf(s[r], LOG2E, lbv));
    if (jit < 15) {
#pragma unroll
      for (int kk = 0; kk < 4; ++kk) b[kk] = bn[kk];
    }
  }
#pragma unroll
  for (int r = 0; r < 16; ++r) {
    int tl = wave * 32 + (r & 3) + 8 * (r >> 2) + 4 * h;
    red2[tl][l31] = racc[r];
  }
  __syncthreads();
  if (tid < 256) {
    float s = 0.f;
#pragma unroll 8
    for (int c = 0; c < 32; ++c) s += red2[tid][c];
    atomicAdd(&rowsum[t0 + tid], s);
  }
}

// ---------------------------------------------------------------------------
// K2b: Hbf_sw = bf16(H*rinv[t]) pre-swizzled to k_z's LDS image.
//      grid 256 x 256.  (Z-zeroing dropped: k_zred overwrites Z fully.)
// ---------------------------------------------------------------------------
__global__ __launch_bounds__(256) void k_scaleH(const float* __restrict__ H,
                                                const float* __restrict__ rowsum,
                                                __bf16* __restrict__ Hbf_sw) {
  __shared__ float rinvL[64];
  const int tid = threadIdx.x;
  const int bx = blockIdx.x;
  const int tblk = bx >> 1, dh = bx & 1;
  const int t0 = tblk * 64;
  if (tid < 64) rinvL[tid] = 1.0f / rowsum[t0 + tid];
  __syncthreads();
#pragma unroll
  for (int itr = 0; itr < 4; ++itr) {
    int idx = itr * 256 + tid;
    int dl = idx >> 3, tbp = idx & 7;
    int d = dh * 128 + dl;
    int swz = (d ^ (d >> 3)) & 7;
    int tloc = (tbp ^ swz) << 3;
    const float4* hp = (const float4*)(H + (size_t)d * T_DIM + t0 + tloc);
    float4 v0 = hp[0], v1 = hp[1];
    float4 r0 = *(const float4*)&rinvL[tloc];
    float4 r1 = *(const float4*)&rinvL[tloc + 4];
    bf16x8 w;
    w[0] = (__bf16)(v0.x * r0.x); w[1] = (__bf16)(v0.y * r0.y);
    w[2] = (__bf16)(v0.z * r0.z); w[3] = (__bf16)(v0.w * r0.w);
    w[4] = (__bf16)(v1.x * r1.x); w[5] = (__bf16)(v1.y * r1.y);
    w[6] = (__bf16)(v1.z * r1.z); w[7] = (__bf16)(v1.w * r1.w);
    *(bf16x8*)(Hbf_sw + (size_t)tblk * 16384 + (size_t)d * 64 + tbp * 8) = w;
  }
}

// ---------------------------------------------------------------------------
// K3: Zp[ts][d][j] = sum_{t in slice} H'[d][t] * E[t][j].
//     R0-proven pipeline, three stall fixes:
//       (1) epilogue: plain plane stores (was 8.4M atomicAdds),
//       (2) aR double-buffered (aR/aRn) via 2x-unrolled loop so the
//           prefetch isn't drained by the same-iter barrier vmcnt(0),
//       (3) s_setprio(1) around the Z-MFMA cluster.
//     grid 512 = 64 j-tiles(128) x 2 d-halves x 4 t-splits; 2 blk/CU.
// ---------------------------------------------------------------------------
__global__ __launch_bounds__(256, 2) void k_z(const __bf16* __restrict__ Hbf_sw,
                                              const __bf16* __restrict__ DHf,
                                              const float* __restrict__ lbe,
                                              float* __restrict__ Zp) {
  __shared__ __bf16 Hs[2][128 * 64];  // [dl][t] swizzled, 2 x 16 KB
  __shared__ __bf16 Pt[2][128 * 64];  // [j][t] swizzled,  2 x 16 KB
  const int tid = threadIdx.x;
  const int lane = tid & 63;
  const int wave = tid >> 6;
  const int h = lane >> 5;
  const int l31 = lane & 31;
  const int bx = blockIdx.x;
  const int ts = bx & 3;
  const int dh = (bx >> 2) & 1;
  const int j0 = (bx >> 3) * 128;
  const int s_tt = wave & 1, s_jg = wave >> 1;
  // resident S-phase B fragments + lbe
  bf16x8 bS[2][4];
  float lbv[2];
#pragma unroll
  for (int q = 0; q < 2; ++q) {
    const size_t Gj = (j0 >> 5) + s_jg * 2 + q;
#pragma unroll
    for (int kk = 0; kk < 4; ++kk)
      bS[q][kk] = *(const bf16x8*)(DHf + Gj * 2048 + kk * 512 + lane * 8);
    lbv[q] = lbe[j0 + (s_jg * 2 + q) * 32 + l31];
  }
  f32x16 acc[2][2];
#pragma unroll
  for (int u = 0; u < 2; ++u)
#pragma unroll
    for (int v = 0; v < 2; ++v) acc[u][v] = zero16();

  // DMA of H' tile 'it_' into Hs[buf_]
#define DMA_HS(buf_, it_)                                                       \
  {                                                                             \
    const __bf16* gsrc =                                                        \
        Hbf_sw + (size_t)(ts * 32 + (it_)) * 16384 + (size_t)dh * 8192;         \
    _Pragma("unroll") for (int r = 0; r < 4; ++r) {                             \
      int chunk = wave * 4 + r;                                                 \
      __builtin_amdgcn_global_load_lds(                                         \
          (const __attribute__((address_space(1))) unsigned int*)(gsrc +        \
              chunk * 512 + lane * 8),                                          \
          (__attribute__((address_space(3))) unsigned int*)(&Hs[buf_][0] +      \
              chunk * 512),                                                     \
          16, 0, 0);                                                            \
    }                                                                           \
  }

  // load A-fragments for t64-tile n_ into register array reg_
#define LOAD_AR(reg_, n_)                                                       \
  {                                                                             \
    const size_t Gt_ = (size_t)(ts * 64 + (n_)*2 + s_tt);                       \
    _Pragma("unroll") for (int kk = 0; kk < 4; ++kk)                            \
        (reg_)[kk] = *(const bf16x8*)(DHf + Gt_ * 2048 + kk * 512 + lane * 8);  \
  }

  // S-phase into Pt[p_] consuming fragment array reg_
#define S_PHASE(p_, reg_)                                                       \
  {                                                                             \
    _Pragma("unroll") for (int q = 0; q < 2; ++q) {                             \
      f32x16 s = zero16();                                                      \
      _Pragma("unroll") for (int kk = 0; kk < 4; ++kk)                          \
          s = __builtin_amdgcn_mfma_f32_32x32x16_bf16((reg_)[kk], bS[q][kk], s, \
                                                      0, 0, 0);                 \
      const int jl = (s_jg * 2 + q) * 32 + l31;                                 \
      const int sj = (jl ^ (jl >> 3)) & 7;                                      \
      _Pragma("unroll") for (int g = 0; g < 4; ++g) {                           \
        const int tl = s_tt * 32 + g * 8 + 4 * h;                               \
        bf16x4 pv;                                                              \
        pv[0] = (__bf16)__builtin_amdgcn_exp2f(                                 \
            __builtin_fmaf(s[g * 4 + 0], LOG2E, lbv[q]));                       \
        pv[1] = (__bf16)__builtin_amdgcn_exp2f(                                 \
            __builtin_fmaf(s[g * 4 + 1], LOG2E, lbv[q]));                       \
        pv[2] = (__bf16)__builtin_amdgcn_exp2f(                                 \
            __builtin_fmaf(s[g * 4 + 2], LOG2E, lbv[q]));                       \
        pv[3] = (__bf16)__builtin_amdgcn_exp2f(                                 \
            __builtin_fmaf(s[g * 4 + 3], LOG2E, lbv[q]));                       \
        const int cchunk = tl >> 3;                                             \
        *(bf16x4*)&Pt[p_][jl * 64 + ((cchunk ^ sj) << 3) + 4 * h] = pv;         \
      }                                                                         \
    }                                                                           \
  }

  // Z-phase consuming buffers p_ (compile-time constant)
#define Z_PHASE(p_)                                                             \
  {                                                                             \
    __builtin_amdgcn_s_setprio(1);                                              \
    _Pragma("unroll") for (int kk = 0; kk < 4; ++kk) {                          \
      const int c = kk * 2 + h;                                                 \
      bf16x8 af[2], bw[2];                                                      \
      _Pragma("unroll") for (int u = 0; u < 2; ++u) {                           \
        int dl = (wave & 1) * 64 + u * 32 + l31;                                \
        af[u] =                                                                 \
            *(const bf16x8*)&Hs[p_][dl * 64 + ((c ^ ((dl ^ (dl >> 3)) & 7)) << 3)]; \
      }                                                                         \
      _Pragma("unroll") for (int v = 0; v < 2; ++v) {                           \
        int j = (wave >> 1) * 64 + v * 32 + l31;                                \
        bw[v] =                                                                 \
            *(const bf16x8*)&Pt[p_][j * 64 + ((c ^ ((j ^ (j >> 3)) & 7)) << 3)]; \
      }                                                                         \
      _Pragma("unroll") for (int u = 0; u < 2; ++u)                             \
          _Pragma("unroll") for (int v = 0; v < 2; ++v)                         \
              acc[u][v] = __builtin_amdgcn_mfma_f32_32x32x16_bf16(              \
                  af[u], bw[v], acc[u][v], 0, 0, 0);                            \
    }                                                                           \
    __builtin_amdgcn_s_setprio(0);                                              \
  }

  bf16x8 aR[4], aRn[4];
  LOAD_AR(aR, 0);
  DMA_HS(0, 0);
  S_PHASE(0, aR);      // Pt[0] for tile 0
  LOAD_AR(aRn, 1);     // frags for tile 1
  __syncthreads();     // Hs[0] drained, Pt[0] visible

  for (int ii = 0; ii < 16; ++ii) {
    const int it0 = ii * 2;
    // ---- even iter: consume Pt/Hs[0]; S builds [1] from aRn; load aR ----
    DMA_HS(1, it0 + 1);
    if (it0 < 30) LOAD_AR(aR, it0 + 2);
    S_PHASE(1, aRn);
    Z_PHASE(0);
    __syncthreads();
    // ---- odd iter: consume [1]; S builds [0] from aR; load aRn ----
    if (it0 + 1 < 31) {
      DMA_HS(0, it0 + 2);
      S_PHASE(0, aR);
    }
    if (it0 + 1 < 30) LOAD_AR(aRn, it0 + 3);
    Z_PHASE(1);
    __syncthreads();
  }
#undef Z_PHASE
#undef S_PHASE
#undef LOAD_AR
#undef DMA_HS
  // ---- epilogue: coalesced plane stores (no atomics) ----
  float* zp = Zp + (size_t)ts * (256 * (size_t)T_DIM);
#pragma unroll
  for (int u = 0; u < 2; ++u)
#pragma unroll
    for (int v = 0; v < 2; ++v)
#pragma unroll
      for (int r = 0; r < 16; ++r) {
        int d = dh * 128 + (wave & 1) * 64 + u * 32 + (r & 3) + 8 * (r >> 2) + 4 * h;
        int j = j0 + (wave >> 1) * 64 + v * 32 + l31;
        zp[(size_t)d * T_DIM + j] = acc[u][v][r];
      }
}

// ---------------------------------------------------------------------------
// K4: Z = l2 * sum_{ts=0..3} Zp[ts]. grid 2048 x 256, pure HBM-bound (~42MB).
// ---------------------------------------------------------------------------
__global__ __launch_bounds__(256) void k_zred(const float* __restrict__ Zp,
                                              const float* __restrict__ l2p,
                                              float* __restrict__ Z) {
  const int i = blockIdx.x * 256 + threadIdx.x;  // 524288 float4s total
  const float l2v = l2p[0];
  const float4* zp4 = (const float4*)Zp;
  float4 a = zp4[i];
#pragma unroll
  for (int s = 1; s < 4; ++s) {
    float4 b = zp4[(size_t)s * 524288 + i];
    a.x += b.x; a.y += b.y; a.z += b.z; a.w += b.w;
  }
  float4 o = {a.x * l2v, a.y * l2v, a.z * l2v, a.w * l2v};
  ((float4*)Z)[i] = o;
}

// ---------------------------------------------------------------------------
extern "C" void kernel_launch(void* const* d_in, const int* in_sizes, int n_in,
                              void* d_out, int out_size, void* d_ws,
                              size_t ws_size, hipStream_t stream) {
  (void)in_sizes; (void)n_in; (void)out_size; (void)ws_size;
  const float* H = (const float*)d_in[0];
  const float* Dm = (const float*)d_in[1];
  const float* l2 = (const float*)d_in[2];
  float* Z = (float*)d_out;
  char* ws = (char*)d_ws;
  __bf16* DHf = (__bf16*)ws;                        // 1,048,576 B
  float* lbe = (float*)(ws + 1048576);              // 32,768 B
  float* rowsum = (float*)(ws + 1048576 + 32768);   // 32,768 B
  __bf16* Hbf_sw = (__bf16*)(ws + 1114112);         // 4,194,304 B
  float* Zp = (float*)(ws + 5308416);               // 33,554,432 B (4 planes)

  k_dh<<<128, 256, 0, stream>>>(H, Dm, DHf, lbe, rowsum);
  k_rowsum<<<512, 512, 0, stream>>>(DHf, lbe, rowsum);
  k_scaleH<<<256, 256, 0, stream>>>(H, rowsum, Hbf_sw);
  k_z<<<512, 256, 0, stream>>>(Hbf_sw, DHf, lbe, Zp);
  k_zred<<<2048, 256, 0, stream>>>(Zp, l2, Z);
}